// Round 6
// baseline (421.598 us; speedup 1.0000x reference)
//
#include <hip/hip_runtime.h>
#include <hip/hip_bf16.h>

typedef __attribute__((ext_vector_type(8))) short short8;
typedef __attribute__((ext_vector_type(4))) float f32x4;
typedef unsigned short u16;

#define DIM     1024
#define NHEAD   16
#define HDIM    64
#define AS1 __attribute__((address_space(1)))
#define AS3 __attribute__((address_space(3)))

__device__ __forceinline__ u16 f2b(float f) {
  union { float f; unsigned u; } v; v.f = f;
  unsigned r = (v.u + 0x7FFFu + ((v.u >> 16) & 1u)) >> 16;
  return (u16)r;
}

// ---------------- convert x fp32 -> bf16 ------------------------------------
__global__ void cvt_x_kernel(const float* __restrict__ in, u16* __restrict__ out, int n8) {
  int i = blockIdx.x * 256 + threadIdx.x;
  if (i >= n8) return;
  const float4* p = (const float4*)in + (size_t)i * 2;
  float4 a = p[0], c = p[1];
  short8 o;
  o[0] = (short)f2b(a.x); o[1] = (short)f2b(a.y); o[2] = (short)f2b(a.z); o[3] = (short)f2b(a.w);
  o[4] = (short)f2b(c.x); o[5] = (short)f2b(c.y); o[6] = (short)f2b(c.z); o[7] = (short)f2b(c.w);
  *((short8*)out + i) = o;
}

// ------------- convert W (K,N) fp32 -> W^T (N,K) bf16, 3 matrices -----------
__global__ void cvt_wT_kernel(const float* __restrict__ Wq, const float* __restrict__ Wk,
                              const float* __restrict__ Wv, u16* __restrict__ wT) {
  int t = blockIdx.x * 256 + threadIdx.x;
  int mat = t >> 17;
  int rem = t & 131071;
  int kg  = rem >> 10;
  int n   = rem & 1023;
  const float* W = (mat == 0) ? Wq : (mat == 1) ? Wk : Wv;
  short8 v;
  #pragma unroll
  for (int i = 0; i < 8; ++i) v[i] = (short)f2b(W[(size_t)(kg * 8 + i) * DIM + n]);
  *(short8*)(wT + ((size_t)mat << 20) + (size_t)n * DIM + kg * 8) = v;
}

// -------- QKV GEMM: persistent 256-block, 256x256 tiles, BK=64, 8-phase -----
// 256 blocks (1/CU, LDS 128KB), 6 tiles/block, flat 96-K-tile pipeline.
// 512 thr = 8 waves (2M x 4N), per-wave 128x64 out (acc[8][4] f32x4).
// LDS: 2 dbuf x { A[256][64] | B[256][64] }; K-tile g -> dbuf[g&1].
// Regions (each read in exactly ONE phase): Ae rows{0-63,128-191} @p1,
// Ao rows{64-127,192-255} @p3, Be rows [0,32)mod64 @p1, Bo [32,64)mod64 @p2.
// Roster: stage K-tile g+2 into dbuf[g&1] right after each region's read:
//   p2: Ae(g+2)  p3: Be(g+2)  p4: Bo(g+2)+Ao(g+2)   (no stage at p1)
// -> every load has a FULL K-tile (4-8 phases) to land before its guard.
// Guard: ONE per K-tile, vmcnt(8) at end-p4 (queue=16: forces exactly tile
// g+1's 8, leaves g+2's 8 in flight). Tail (g>=94): vmcnt(0), cheap.
// Overwrite-safe: stage issues >=1 barrier after target region's only read.
// Tiles roll seamlessly: stage coords advance at g%16==14; epilogue after
// g%16==15's guard overlaps the next tile's in-flight prefetch.
#define VMW_(n) asm volatile("s_waitcnt vmcnt(" #n ")" ::: "memory")
#define VMW(n) VMW_(n)

#define STAGE2(isB, isOdd, srcp, koff, dbit) do { \
  _Pragma("unroll") \
  for (int _j = 0; _j < 2; ++_j) { \
    int _b = _j * 8 + wid; \
    int _r0 = (isB) ? (((_b >> 2) << 6) + ((_b & 3) << 3) + ((isOdd) << 5)) \
                    : (((_b >> 3) << 7) + ((_b & 7) << 3) + ((isOdd) << 6)); \
    __builtin_amdgcn_global_load_lds( \
      (const AS1 void*)((srcp) + (size_t)_r0 * DIM + (koff)), \
      (AS3 void*)(lds + ((dbit) + ((isB) << 14) + _r0 * 64)), \
      16, 0, 0); \
  } \
} while (0)

#define LDA(d, g) do { \
  _Pragma("unroll") \
  for (int _mi = 0; _mi < 4; ++_mi) { \
    int _r = abase + ((g) * 4 + _mi) * 1024 + ((d) << 15); \
    a[_mi * 2]     = *(const short8*)(lds + _r + sx0); \
    a[_mi * 2 + 1] = *(const short8*)(lds + _r + sx1); \
  } \
} while (0)

#define LDB(d, dst, nB) do { \
  _Pragma("unroll") \
  for (int _ni = 0; _ni < 2; ++_ni) { \
    int _r = bbase + ((nB) + _ni) * 1024 + ((d) << 15) + 16384; \
    dst[_ni * 2]     = *(const short8*)(lds + _r + sx0); \
    dst[_ni * 2 + 1] = *(const short8*)(lds + _r + sx1); \
  } \
} while (0)

#define MF(g, nB, bset) do { \
  _Pragma("unroll") \
  for (int _mi = 0; _mi < 4; ++_mi) \
    _Pragma("unroll") \
    for (int _ni = 0; _ni < 2; ++_ni) \
      _Pragma("unroll") \
      for (int _kk = 0; _kk < 2; ++_kk) \
        acc[(g) * 4 + _mi][(nB) + _ni] = __builtin_amdgcn_mfma_f32_16x16x32_bf16( \
            a[_mi * 2 + _kk], bset[_ni * 2 + _kk], acc[(g) * 4 + _mi][(nB) + _ni], 0, 0, 0); \
} while (0)

#define PH_MID() do { \
  __builtin_amdgcn_s_barrier(); \
  asm volatile("s_waitcnt lgkmcnt(0)" ::: "memory"); \
  __builtin_amdgcn_sched_barrier(0); \
  __builtin_amdgcn_s_setprio(1); \
} while (0)

#define PH_END() do { \
  __builtin_amdgcn_s_setprio(0); \
  __builtin_amdgcn_s_barrier(); \
} while (0)

// One K-tile (4 phases). d = dbuf bit; SDO = stage K-tile g+2; GZ = tail guard
#define GROUP(d, SDO, koff, GZ) do { \
  /* p1: read Ae + Be (12 ds_reads); no stage */ \
  LDA(d, 0); LDB(d, b01, 0); \
  asm volatile("s_waitcnt lgkmcnt(8)" ::: "memory"); \
  PH_MID(); MF(0, 0, b01); PH_END(); \
  /* p2: read Bo; stage Ae(g+2) */ \
  LDB(d, b23, 2); \
  if (SDO) STAGE2(0, 0, srcA_s, koff, (d) << 15); \
  PH_MID(); MF(0, 2, b23); PH_END(); \
  /* p3: read Ao; stage Be(g+2) */ \
  LDA(d, 1); \
  if (SDO) STAGE2(1, 0, srcB_s, koff, (d) << 15); \
  PH_MID(); MF(1, 2, b23); PH_END(); \
  /* p4: all-reg; stage Bo(g+2)+Ao(g+2); single counted guard */ \
  if (SDO) { STAGE2(1, 1, srcB_s, koff, (d) << 15); STAGE2(0, 1, srcA_s, koff, (d) << 15); } \
  PH_MID(); MF(1, 0, b01); \
  __builtin_amdgcn_s_setprio(0); \
  if (GZ) { VMW(0); } else { VMW(8); } \
  __builtin_amdgcn_s_barrier(); \
} while (0)

__global__ __launch_bounds__(512, 2) void qkv_gemm_kernel(
    const u16* __restrict__ xb, const u16* __restrict__ wT,
    const float* __restrict__ bq, const float* __restrict__ bk, const float* __restrict__ bv,
    u16* __restrict__ qb, u16* __restrict__ kb, u16* __restrict__ vb)
{
  __shared__ u16 lds[65536];   // 128 KiB -> 1 block/CU

  const int tid  = threadIdx.x;
  const int lane = tid & 63;
  const int wid  = tid >> 6;

  // persistent mapping: block -> XCD chunk of 192 tiles, 6 consecutive tiles
  const int blk  = blockIdx.x;           // 0..255
  const int xcd  = blk & 7;
  const int slot = blk >> 3;             // 0..31
  const int wg0  = xcd * 192 + slot * 6;

  const int wr = wid >> 2;               // 0..1
  const int wc = wid & 3;                // 0..3
  const int l15 = lane & 15, lhi = lane >> 4;

  const int sr = lane >> 3;              // row within 8-row block
  const int sl = (lane & 7) ^ sr;        // pre-swizzled logical 16B slot

  // fragment phys-slot offsets (elems): phys = logical ^ (row&7)
  const int sx0 = (lhi ^ (l15 & 7)) << 3;
  const int sx1 = ((4 + lhi) ^ (l15 & 7)) << 3;
  const int abase = (wr * 128 + l15) * 64;
  const int bbase = (wc * 64 + l15) * 64;

  // staging-side tile coords (tile 0 first)
  int tS = 0;
  int bmS = (wg0) / 12, bnS = (wg0) % 12;
  const u16* srcA_s = xb + (size_t)(((bmS << 8)) + sr) * DIM + sl * 8;
  const u16* srcB_s = wT + ((size_t)(bnS >> 2) << 20) + (size_t)(((bnS & 3) << 8) + sr) * DIM + sl * 8;

  f32x4 acc[8][4] = {};
  short8 a[8], b01[4], b23[4];

  // prologue: K-tiles 0 and 1 fully staged (16 loads); vmcnt(8) forces kt0
  STAGE2(0, 0, srcA_s, 0, 0);     STAGE2(1, 0, srcB_s, 0, 0);
  STAGE2(1, 1, srcB_s, 0, 0);     STAGE2(0, 1, srcA_s, 0, 0);
  STAGE2(0, 0, srcA_s, 64, 32768); STAGE2(1, 0, srcB_s, 64, 32768);
  STAGE2(1, 1, srcB_s, 64, 32768); STAGE2(0, 1, srcA_s, 64, 32768);
  VMW(8);
  __builtin_amdgcn_s_barrier();

  #pragma unroll 1
  for (int g = 0; g < 96; g += 2) {
    // advance staging coords when gs = g+2 crosses into the next tile
    if ((g & 15) == 14 && g < 90) {
      ++tS;
      int wgn = wg0 + tS;
      int bmN = wgn / 12, bnN = wgn % 12;
      srcA_s = xb + (size_t)((bmN << 8) + sr) * DIM + sl * 8;
      srcB_s = wT + ((size_t)(bnN >> 2) << 20) + (size_t)(((bnN & 3) << 8) + sr) * DIM + sl * 8;
    }
    const int k2 = ((g + 2) & 15) * 64;
    const int k3 = ((g + 3) & 15) * 64;
    const bool sdo = (g < 94);
    const bool gz  = (g >= 94);

    GROUP(0, sdo, k2, gz);
    GROUP(1, sdo, k3, gz);

    // tile finished -> epilogue (overlaps next tile's in-flight prefetch)
    if ((g & 15) == 14) {
      int Te = g >> 4;
      int wge = wg0 + Te;
      int bmE = wge / 12, bnE = wge % 12;
      int matE = bnE >> 2;
      int col0 = (bnE & 3) << 8;
      int row0 = bmE << 8;
      const float* bias = (matE == 0) ? bq : (matE == 1) ? bk : bv;
      u16* outp = (matE == 0) ? qb : (matE == 1) ? kb : vb;
      #pragma unroll
      for (int ni = 0; ni < 4; ++ni) {
        int gcol = col0 + wc * 64 + ni * 16 + l15;
        float bb = bias[gcol];
        #pragma unroll
        for (int mi = 0; mi < 8; ++mi) {
          int grow = row0 + wr * 128 + mi * 16 + (lhi << 2);
          #pragma unroll
          for (int r = 0; r < 4; ++r)
            outp[(size_t)(grow + r) * DIM + gcol] = f2b(acc[mi][ni][r] + bb);
        }
      }
      #pragma unroll
      for (int mi = 0; mi < 8; ++mi)
        #pragma unroll
        for (int ni = 0; ni < 4; ++ni)
          acc[mi][ni] = f32x4{0.f, 0.f, 0.f, 0.f};
    }
  }
}

// ---------------- block-diagonal attention: one WG per (b, blk, h) -----------
__global__ __launch_bounds__(256) void blk_attn_kernel(
    const u16* __restrict__ qb, const u16* __restrict__ kb, const u16* __restrict__ vb,
    float* __restrict__ out)
{
  __shared__ u16 qs[64 * 72];
  __shared__ u16 ks[64 * 72];
  __shared__ u16 vts[64 * 72];
  __shared__ u16 ps[64 * 72];

  const int tid  = threadIdx.x;
  const int lane = tid & 63;
  const int wid  = tid >> 6;
  const int idx  = blockIdx.x;
  const int h    = idx & 15;
  const int blk  = (idx >> 4) & 127;
  const int b    = idx >> 11;
  const size_t s0 = (size_t)b * 8192 + (size_t)blk * 64;
  const int h0 = h * HDIM;

  {
    int i  = tid >> 2;
    int cg = (tid & 3) * 16;
    const u16* qg = qb + (s0 + i) * DIM + h0 + cg;
    *(short8*)(qs + i * 72 + cg)     = *(const short8*)qg;
    *(short8*)(qs + i * 72 + cg + 8) = *(const short8*)(qg + 8);
    const u16* kg = kb + (s0 + i) * DIM + h0 + cg;
    *(short8*)(ks + i * 72 + cg)     = *(const short8*)kg;
    *(short8*)(ks + i * 72 + cg + 8) = *(const short8*)(kg + 8);
    const u16* vg = vb + (s0 + i) * DIM + h0 + cg;
    short8 v0 = *(const short8*)vg;
    short8 v1 = *(const short8*)(vg + 8);
    #pragma unroll
    for (int e = 0; e < 8; ++e) {
      vts[(cg + e) * 72 + i]     = (u16)v0[e];
      vts[(cg + 8 + e) * 72 + i] = (u16)v1[e];
    }
  }
  __syncthreads();

  f32x4 S[4] = {};
  {
    short8 aq[2];
    #pragma unroll
    for (int kk = 0; kk < 2; ++kk)
      aq[kk] = *(const short8*)(qs + (wid * 16 + (lane & 15)) * 72 + kk * 32 + ((lane >> 4) << 3));
    #pragma unroll
    for (int jt = 0; jt < 4; ++jt)
      #pragma unroll
      for (int kk = 0; kk < 2; ++kk) {
        short8 bk_ = *(const short8*)(ks + (jt * 16 + (lane & 15)) * 72 + kk * 32 + ((lane >> 4) << 3));
        S[jt] = __builtin_amdgcn_mfma_f32_16x16x32_bf16(aq[kk], bk_, S[jt], 0, 0, 0);
      }
  }

  const float scale = 0.125f;
  float rinv[4];
  #pragma unroll
  for (int r = 0; r < 4; ++r) {
    float m = S[0][r] * scale;
    #pragma unroll
    for (int jt = 1; jt < 4; ++jt) m = fmaxf(m, S[jt][r] * scale);
    #pragma unroll
    for (int off = 1; off < 16; off <<= 1) m = fmaxf(m, __shfl_xor(m, off, 64));
    float s = 0.f;
    #pragma unroll
    for (int jt = 0; jt < 4; ++jt) {
      float e = __expf(S[jt][r] * scale - m);
      S[jt][r] = e;
      s += e;
    }
    #pragma unroll
    for (int off = 1; off < 16; off <<= 1) s += __shfl_xor(s, off, 64);
    rinv[r] = 1.0f / s;
  }

  #pragma unroll
  for (int jt = 0; jt < 4; ++jt)
    #pragma unroll
    for (int r = 0; r < 4; ++r)
      ps[(wid * 16 + ((lane >> 4) << 2) + r) * 72 + jt * 16 + (lane & 15)] = f2b(S[jt][r]);
  __syncthreads();

  f32x4 O[4] = {};
  {
    short8 pa[2];
    #pragma unroll
    for (int kk = 0; kk < 2; ++kk)
      pa[kk] = *(const short8*)(ps + (wid * 16 + (lane & 15)) * 72 + kk * 32 + ((lane >> 4) << 3));
    #pragma unroll
    for (int dt = 0; dt < 4; ++dt)
      #pragma unroll
      for (int kk = 0; kk < 2; ++kk) {
        short8 bv_ = *(const short8*)(vts + (dt * 16 + (lane & 15)) * 72 + kk * 32 + ((lane >> 4) << 3));
        O[dt] = __builtin_amdgcn_mfma_f32_16x16x32_bf16(pa[kk], bv_, O[dt], 0, 0, 0);
      }
  }

  #pragma unroll
  for (int dt = 0; dt < 4; ++dt)
    #pragma unroll
    for (int r = 0; r < 4; ++r)
      out[(s0 + wid * 16 + ((lane >> 4) << 2) + r) * DIM + h0 + dt * 16 + (lane & 15)] = O[dt][r] * rinv[r];
}

extern "C" void kernel_launch(void* const* d_in, const int* in_sizes, int n_in,
                              void* d_out, int out_size, void* d_ws, size_t ws_size,
                              hipStream_t stream) {
  const float* x  = (const float*)d_in[0];
  const float* Wq = (const float*)d_in[1];
  const float* bq = (const float*)d_in[2];
  const float* Wk = (const float*)d_in[3];
  const float* bk = (const float*)d_in[4];
  const float* Wv = (const float*)d_in[5];
  const float* bv = (const float*)d_in[6];
  float* out = (float*)d_out;

  char* ws = (char*)d_ws;
  u16* xb = (u16*)ws;                          // 67,108,864 B
  u16* wT = (u16*)(ws + 67108864);             // 6,291,456 B
  u16* qb = (u16*)(ws + 73400320);             // 67,108,864 B
  u16* kb = (u16*)(ws + 140509184);            // 67,108,864 B
  u16* vb = (u16*)(ws + 207618048);            // 67,108,864 B

  cvt_x_kernel<<<16384, 256, 0, stream>>>(x, xb, 4194304);
  cvt_wT_kernel<<<1536, 256, 0, stream>>>(Wq, Wk, Wv, wT);
  qkv_gemm_kernel<<<256, 512, 0, stream>>>(xb, wT, bq, bk, bv, qb, kb, vb);
  blk_attn_kernel<<<8192, 256, 0, stream>>>(qb, kb, vb, out);
}

// Round 7
// 320.879 us; speedup vs baseline: 1.3139x; 1.3139x over previous
//
#include <hip/hip_runtime.h>
#include <hip/hip_bf16.h>

typedef __attribute__((ext_vector_type(8))) short short8;
typedef __attribute__((ext_vector_type(4))) float f32x4;
typedef unsigned short u16;

#define DIM     1024
#define NHEAD   16
#define HDIM    64
#define AS1 __attribute__((address_space(1)))
#define AS3 __attribute__((address_space(3)))

__device__ __forceinline__ u16 f2b(float f) {
  union { float f; unsigned u; } v; v.f = f;
  unsigned r = (v.u + 0x7FFFu + ((v.u >> 16) & 1u)) >> 16;
  return (u16)r;
}

// ---------------- convert x fp32 -> bf16 ------------------------------------
__global__ void cvt_x_kernel(const float* __restrict__ in, u16* __restrict__ out, int n8) {
  int i = blockIdx.x * 256 + threadIdx.x;
  if (i >= n8) return;
  const float4* p = (const float4*)in + (size_t)i * 2;
  float4 a = p[0], c = p[1];
  short8 o;
  o[0] = (short)f2b(a.x); o[1] = (short)f2b(a.y); o[2] = (short)f2b(a.z); o[3] = (short)f2b(a.w);
  o[4] = (short)f2b(c.x); o[5] = (short)f2b(c.y); o[6] = (short)f2b(c.z); o[7] = (short)f2b(c.w);
  *((short8*)out + i) = o;
}

// ------------- convert W (K,N) fp32 -> W^T (N,K) bf16, 3 matrices -----------
__global__ void cvt_wT_kernel(const float* __restrict__ Wq, const float* __restrict__ Wk,
                              const float* __restrict__ Wv, u16* __restrict__ wT) {
  int t = blockIdx.x * 256 + threadIdx.x;
  int mat = t >> 17;
  int rem = t & 131071;
  int kg  = rem >> 10;
  int n   = rem & 1023;
  const float* W = (mat == 0) ? Wq : (mat == 1) ? Wk : Wv;
  short8 v;
  #pragma unroll
  for (int i = 0; i < 8; ++i) v[i] = (short)f2b(W[(size_t)(kg * 8 + i) * DIM + n]);
  *(short8*)(wT + ((size_t)mat << 20) + (size_t)n * DIM + kg * 8) = v;
}

// ---------------- QKV GEMM: 256x256 tile, BK=64, R3 schedule (848 TF) -------
// EXACT restore of the round-3 K-loop (best measured: 243 us, correctly
// guarded: end-p4 vmcnt(2) forces kt+1 exactly; end-p8 vmcnt(4) forces kt+2
// exactly; queue never drains in steady state). New: vectorized epilogue via
// per-wave LDS-bounce transpose (fixes 1.7x WRITE_SIZE from scalar 2B RMW).
#define STAGE(matB, h, ktile) do { \
  _Pragma("unroll") \
  for (int _j = 0; _j < 2; ++_j) { \
    int _c = _j * 8 + wid; \
    __builtin_amdgcn_global_load_lds( \
      (const AS1 void*)(((matB) ? srcB : srcA) + (size_t)((h) * 128 + _c * 8) * DIM + (ktile) * 64), \
      (AS3 void*)(lds + ((((ktile) & 1) << 15) + ((matB) << 14) + ((h) << 13) + _c * 512)), \
      16, 0, 0); \
  } \
} while (0)

#define LDA(d, g) do { \
  _Pragma("unroll") \
  for (int _mi = 0; _mi < 4; ++_mi) { \
    int _r = abase + ((g) * 4 + _mi) * 1024 + ((d) << 15); \
    a[_mi * 2]     = *(const short8*)(lds + _r + sx0); \
    a[_mi * 2 + 1] = *(const short8*)(lds + _r + sx1); \
  } \
} while (0)

#define LDB(d, dst, nB) do { \
  _Pragma("unroll") \
  for (int _ni = 0; _ni < 2; ++_ni) { \
    int _r = bbase + ((nB) + _ni) * 1024 + ((d) << 15) + 16384; \
    dst[_ni * 2]     = *(const short8*)(lds + _r + sx0); \
    dst[_ni * 2 + 1] = *(const short8*)(lds + _r + sx1); \
  } \
} while (0)

#define MF(g, nB, bset) do { \
  _Pragma("unroll") \
  for (int _mi = 0; _mi < 4; ++_mi) \
    _Pragma("unroll") \
    for (int _ni = 0; _ni < 2; ++_ni) \
      _Pragma("unroll") \
      for (int _kk = 0; _kk < 2; ++_kk) \
        acc[(g) * 4 + _mi][(nB) + _ni] = __builtin_amdgcn_mfma_f32_16x16x32_bf16( \
            a[_mi * 2 + _kk], bset[_ni * 2 + _kk], acc[(g) * 4 + _mi][(nB) + _ni], 0, 0, 0); \
} while (0)

#define PH_MID() do { \
  __builtin_amdgcn_s_barrier(); \
  asm volatile("s_waitcnt lgkmcnt(0)" ::: "memory"); \
  __builtin_amdgcn_sched_barrier(0); \
  __builtin_amdgcn_s_setprio(1); \
} while (0)

#define PH_END() do { \
  __builtin_amdgcn_s_setprio(0); \
  __builtin_amdgcn_s_barrier(); \
} while (0)

#define PH_END_VM(n) do { \
  __builtin_amdgcn_s_setprio(0); \
  asm volatile("s_waitcnt vmcnt(" #n ")" ::: "memory"); \
  __builtin_amdgcn_s_barrier(); \
} while (0)

__global__ __launch_bounds__(512, 2) void qkv_gemm_kernel(
    const u16* __restrict__ xb, const u16* __restrict__ wT,
    const float* __restrict__ bq, const float* __restrict__ bk, const float* __restrict__ bv,
    u16* __restrict__ qb, u16* __restrict__ kb, u16* __restrict__ vb)
{
  __shared__ u16 lds[65536];   // 128 KiB

  const int tid  = threadIdx.x;
  const int lane = tid & 63;
  const int wid  = tid >> 6;

  // XCD-chunked bijective swizzle: 1536 = 8 XCDs x 192
  const int orig = blockIdx.x;
  const int wg   = (orig & 7) * 192 + (orig >> 3);
  const int bm   = wg / 12;
  const int bn   = wg % 12;
  const int mat  = bn >> 2;
  const int col0 = (bn & 3) << 8;
  const int row0 = bm << 8;
  const u16* Wm = wT + ((size_t)mat << 20);
  const float* bias = (mat == 0) ? bq : (mat == 1) ? bk : bv;
  u16* outp = (mat == 0) ? qb : (mat == 1) ? kb : vb;

  const int wr = wid >> 2;             // 0..1
  const int wc = wid & 3;              // 0..3
  const int l15 = lane & 15, lhi = lane >> 4;

  // staging source (pre-swizzled so LDS dest stays linear)
  const int sr = lane >> 3;            // row within 8-row block
  const int sl = (lane & 7) ^ sr;      // logical 16B slot
  const u16* srcA = xb + (size_t)(row0 + sr) * DIM + sl * 8;
  const u16* srcB = Wm + (size_t)(col0 + sr) * DIM + sl * 8;

  // fragment phys-slot offsets (elems): phys = logical ^ (row&7)
  const int sx0 = (lhi ^ (l15 & 7)) << 3;
  const int sx1 = ((4 + lhi) ^ (l15 & 7)) << 3;
  const int abase = (wr * 128 + l15) * 64;
  const int bbase = (wc * 64 + l15) * 64;

  f32x4 acc[8][4] = {};
  short8 a[8], b01[4], b23[4];

  // prologue: kt0 fully + kt1 A halves; vmcnt(4) forces kt0, leaves kt1.A
  STAGE(0, 0, 0); STAGE(0, 1, 0); STAGE(1, 0, 0); STAGE(1, 1, 0);
  STAGE(0, 0, 1); STAGE(0, 1, 1);
  asm volatile("s_waitcnt vmcnt(4)" ::: "memory");
  __builtin_amdgcn_s_barrier();

  #pragma unroll 1
  for (int t = 0; t < 8; ++t) {
    const int kt = 2 * t;
    const bool pf = (t < 7);
    // ---- K-tile kt (dbuf0) ----
    // p1
    LDA(0, 0); LDB(0, b01, 0);
    STAGE(1, 0, kt + 1);
    asm volatile("s_waitcnt lgkmcnt(8)" ::: "memory");
    PH_MID(); MF(0, 0, b01); PH_END();
    // p2
    LDB(0, b23, 2);
    STAGE(1, 1, kt + 1);
    PH_MID(); MF(0, 2, b23); PH_END();
    // p3
    LDA(0, 1);
    PH_MID(); MF(1, 2, b23); PH_END();
    // p4 (b01 still live in regs)
    if (pf) STAGE(0, 0, kt + 2);
    PH_MID(); MF(1, 0, b01);
    if (pf) { PH_END_VM(2); } else { PH_END_VM(0); }
    // ---- K-tile kt+1 (dbuf1) ----
    // p5
    LDA(1, 0); LDB(1, b01, 0);
    if (pf) STAGE(0, 1, kt + 2);
    asm volatile("s_waitcnt lgkmcnt(8)" ::: "memory");
    PH_MID(); MF(0, 0, b01); PH_END();
    // p6
    LDB(1, b23, 2);
    if (pf) STAGE(1, 0, kt + 2);
    PH_MID(); MF(0, 2, b23); PH_END();
    // p7
    LDA(1, 1);
    if (pf) STAGE(1, 1, kt + 2);
    PH_MID(); MF(1, 2, b23); PH_END();
    // p8
    if (pf) { STAGE(0, 0, kt + 3); STAGE(0, 1, kt + 3); }
    PH_MID(); MF(1, 0, b01);
    if (pf) { PH_END_VM(4); } else { PH_END_VM(0); }
  }

  // ---- epilogue: bias + LDS-bounce transpose -> coalesced 16B stores ------
  // All staging forced (tail vmcnt(0)) and all K-loop ds_reads complete;
  // each wave reuses its private 16 KiB (ep[128][64], 16B-slot XOR swizzle).
  {
    u16* ep = lds + wid * 8192;
    #pragma unroll
    for (int ni = 0; ni < 4; ++ni) {
      int gcol = col0 + wc * 64 + ni * 16 + l15;
      float bb = bias[gcol];
      #pragma unroll
      for (int mi = 0; mi < 8; ++mi)
        #pragma unroll
        for (int r = 0; r < 4; ++r) {
          int lr = mi * 16 + (lhi << 2) + r;
          int lc = ni * 16 + l15;
          ep[lr * 64 + (((lc >> 3) ^ (lr & 7)) << 3) + (lc & 7)] = f2b(acc[mi][ni][r] + bb);
        }
    }
    const int rr = lane >> 3;          // 0..7
    const int cc = lane & 7;           // 0..7
    u16* obase = outp + (size_t)(row0 + wr * 128) * DIM + col0 + wc * 64 + cc * 8;
    #pragma unroll
    for (int it = 0; it < 16; ++it) {
      int lr = it * 8 + rr;
      short8 v = *(const short8*)(ep + lr * 64 + ((cc ^ (lr & 7)) << 3));
      *(short8*)(obase + (size_t)lr * DIM) = v;
    }
  }
}

// ---------------- block-diagonal attention: one WG per (b, blk, h) -----------
__global__ __launch_bounds__(256) void blk_attn_kernel(
    const u16* __restrict__ qb, const u16* __restrict__ kb, const u16* __restrict__ vb,
    float* __restrict__ out)
{
  __shared__ u16 qs[64 * 72];
  __shared__ u16 ks[64 * 72];
  __shared__ u16 vts[64 * 72];
  __shared__ u16 ps[64 * 72];

  const int tid  = threadIdx.x;
  const int lane = tid & 63;
  const int wid  = tid >> 6;
  const int idx  = blockIdx.x;
  const int h    = idx & 15;
  const int blk  = (idx >> 4) & 127;
  const int b    = idx >> 11;
  const size_t s0 = (size_t)b * 8192 + (size_t)blk * 64;
  const int h0 = h * HDIM;

  {
    int i  = tid >> 2;
    int cg = (tid & 3) * 16;
    const u16* qg = qb + (s0 + i) * DIM + h0 + cg;
    *(short8*)(qs + i * 72 + cg)     = *(const short8*)qg;
    *(short8*)(qs + i * 72 + cg + 8) = *(const short8*)(qg + 8);
    const u16* kg = kb + (s0 + i) * DIM + h0 + cg;
    *(short8*)(ks + i * 72 + cg)     = *(const short8*)kg;
    *(short8*)(ks + i * 72 + cg + 8) = *(const short8*)(kg + 8);
    const u16* vg = vb + (s0 + i) * DIM + h0 + cg;
    short8 v0 = *(const short8*)vg;
    short8 v1 = *(const short8*)(vg + 8);
    #pragma unroll
    for (int e = 0; e < 8; ++e) {
      vts[(cg + e) * 72 + i]     = (u16)v0[e];
      vts[(cg + 8 + e) * 72 + i] = (u16)v1[e];
    }
  }
  __syncthreads();

  f32x4 S[4] = {};
  {
    short8 aq[2];
    #pragma unroll
    for (int kk = 0; kk < 2; ++kk)
      aq[kk] = *(const short8*)(qs + (wid * 16 + (lane & 15)) * 72 + kk * 32 + ((lane >> 4) << 3));
    #pragma unroll
    for (int jt = 0; jt < 4; ++jt)
      #pragma unroll
      for (int kk = 0; kk < 2; ++kk) {
        short8 bk_ = *(const short8*)(ks + (jt * 16 + (lane & 15)) * 72 + kk * 32 + ((lane >> 4) << 3));
        S[jt] = __builtin_amdgcn_mfma_f32_16x16x32_bf16(aq[kk], bk_, S[jt], 0, 0, 0);
      }
  }

  const float scale = 0.125f;
  float rinv[4];
  #pragma unroll
  for (int r = 0; r < 4; ++r) {
    float m = S[0][r] * scale;
    #pragma unroll
    for (int jt = 1; jt < 4; ++jt) m = fmaxf(m, S[jt][r] * scale);
    #pragma unroll
    for (int off = 1; off < 16; off <<= 1) m = fmaxf(m, __shfl_xor(m, off, 64));
    float s = 0.f;
    #pragma unroll
    for (int jt = 0; jt < 4; ++jt) {
      float e = __expf(S[jt][r] * scale - m);
      S[jt][r] = e;
      s += e;
    }
    #pragma unroll
    for (int off = 1; off < 16; off <<= 1) s += __shfl_xor(s, off, 64);
    rinv[r] = 1.0f / s;
  }

  #pragma unroll
  for (int jt = 0; jt < 4; ++jt)
    #pragma unroll
    for (int r = 0; r < 4; ++r)
      ps[(wid * 16 + ((lane >> 4) << 2) + r) * 72 + jt * 16 + (lane & 15)] = f2b(S[jt][r]);
  __syncthreads();

  f32x4 O[4] = {};
  {
    short8 pa[2];
    #pragma unroll
    for (int kk = 0; kk < 2; ++kk)
      pa[kk] = *(const short8*)(ps + (wid * 16 + (lane & 15)) * 72 + kk * 32 + ((lane >> 4) << 3));
    #pragma unroll
    for (int dt = 0; dt < 4; ++dt)
      #pragma unroll
      for (int kk = 0; kk < 2; ++kk) {
        short8 bv_ = *(const short8*)(vts + (dt * 16 + (lane & 15)) * 72 + kk * 32 + ((lane >> 4) << 3));
        O[dt] = __builtin_amdgcn_mfma_f32_16x16x32_bf16(pa[kk], bv_, O[dt], 0, 0, 0);
      }
  }

  #pragma unroll
  for (int dt = 0; dt < 4; ++dt)
    #pragma unroll
    for (int r = 0; r < 4; ++r)
      out[(s0 + wid * 16 + ((lane >> 4) << 2) + r) * DIM + h0 + dt * 16 + (lane & 15)] = O[dt][r] * rinv[r];
}

extern "C" void kernel_launch(void* const* d_in, const int* in_sizes, int n_in,
                              void* d_out, int out_size, void* d_ws, size_t ws_size,
                              hipStream_t stream) {
  const float* x  = (const float*)d_in[0];
  const float* Wq = (const float*)d_in[1];
  const float* bq = (const float*)d_in[2];
  const float* Wk = (const float*)d_in[3];
  const float* bk = (const float*)d_in[4];
  const float* Wv = (const float*)d_in[5];
  const float* bv = (const float*)d_in[6];
  float* out = (float*)d_out;

  char* ws = (char*)d_ws;
  u16* xb = (u16*)ws;                          // 67,108,864 B
  u16* wT = (u16*)(ws + 67108864);             // 6,291,456 B
  u16* qb = (u16*)(ws + 73400320);             // 67,108,864 B
  u16* kb = (u16*)(ws + 140509184);            // 67,108,864 B
  u16* vb = (u16*)(ws + 207618048);            // 67,108,864 B

  cvt_x_kernel<<<16384, 256, 0, stream>>>(x, xb, 4194304);
  cvt_wT_kernel<<<1536, 256, 0, stream>>>(Wq, Wk, Wv, wT);
  qkv_gemm_kernel<<<1536, 512, 0, stream>>>(xb, wT, bq, bk, bv, qb, kb, vb);
  blk_attn_kernel<<<8192, 256, 0, stream>>>(qb, kb, vb, out);
}

// Round 8
// 315.252 us; speedup vs baseline: 1.3373x; 1.0178x over previous
//
#include <hip/hip_runtime.h>
#include <hip/hip_bf16.h>

typedef __attribute__((ext_vector_type(8))) short short8;
typedef __attribute__((ext_vector_type(4))) float f32x4;
typedef unsigned short u16;

#define DIM     1024
#define NHEAD   16
#define HDIM    64
#define AS1 __attribute__((address_space(1)))
#define AS3 __attribute__((address_space(3)))

__device__ __forceinline__ u16 f2b(float f) {
  union { float f; unsigned u; } v; v.f = f;
  unsigned r = (v.u + 0x7FFFu + ((v.u >> 16) & 1u)) >> 16;
  return (u16)r;
}

// ------- fused convert: x fp32->bf16 (blocks 0..16383) ; W->W^T bf16 --------
// Clean split: blocks < 16384 handle x (thread i: 8 elems); blocks >= 16384
// handle the 3 weight matrices' transpose-convert (393216 threads).
__global__ void cvt_fused_kernel(const float* __restrict__ x,
                                 const float* __restrict__ Wq, const float* __restrict__ Wk,
                                 const float* __restrict__ Wv,
                                 u16* __restrict__ xb, u16* __restrict__ wT) {
  int i = blockIdx.x * 256 + threadIdx.x;
  if (i < 4194304) {
    const float4* p = (const float4*)x + (size_t)i * 2;
    float4 a = p[0], c = p[1];
    short8 o;
    o[0] = (short)f2b(a.x); o[1] = (short)f2b(a.y); o[2] = (short)f2b(a.z); o[3] = (short)f2b(a.w);
    o[4] = (short)f2b(c.x); o[5] = (short)f2b(c.y); o[6] = (short)f2b(c.z); o[7] = (short)f2b(c.w);
    *((short8*)xb + i) = o;
  } else {
    int t = i - 4194304;             // 0..393215
    int mat = t >> 17;
    int rem = t & 131071;
    int kg  = rem >> 10;
    int n   = rem & 1023;
    const float* W = (mat == 0) ? Wq : (mat == 1) ? Wk : Wv;
    short8 v;
    #pragma unroll
    for (int e = 0; e < 8; ++e) v[e] = (short)f2b(W[(size_t)(kg * 8 + e) * DIM + n]);
    *(short8*)(wT + ((size_t)mat << 20) + (size_t)n * DIM + kg * 8) = v;
  }
}

// ---------------- QKV GEMM: 256x256 tile, BK=64, R3 schedule (848 TF) -------
// Structure ceiling at K=1024 per m248 (counted guards vmcnt(2)/(4), region-
// split roster, T1+T2+T5). Epilogue: per-wave LDS-bounce -> coalesced stores.
#define STAGE(matB, h, ktile) do { \
  _Pragma("unroll") \
  for (int _j = 0; _j < 2; ++_j) { \
    int _c = _j * 8 + wid; \
    __builtin_amdgcn_global_load_lds( \
      (const AS1 void*)(((matB) ? srcB : srcA) + (size_t)((h) * 128 + _c * 8) * DIM + (ktile) * 64), \
      (AS3 void*)(lds + ((((ktile) & 1) << 15) + ((matB) << 14) + ((h) << 13) + _c * 512)), \
      16, 0, 0); \
  } \
} while (0)

#define LDA(d, g) do { \
  _Pragma("unroll") \
  for (int _mi = 0; _mi < 4; ++_mi) { \
    int _r = abase + ((g) * 4 + _mi) * 1024 + ((d) << 15); \
    a[_mi * 2]     = *(const short8*)(lds + _r + sx0); \
    a[_mi * 2 + 1] = *(const short8*)(lds + _r + sx1); \
  } \
} while (0)

#define LDB(d, dst, nB) do { \
  _Pragma("unroll") \
  for (int _ni = 0; _ni < 2; ++_ni) { \
    int _r = bbase + ((nB) + _ni) * 1024 + ((d) << 15) + 16384; \
    dst[_ni * 2]     = *(const short8*)(lds + _r + sx0); \
    dst[_ni * 2 + 1] = *(const short8*)(lds + _r + sx1); \
  } \
} while (0)

#define MF(g, nB, bset) do { \
  _Pragma("unroll") \
  for (int _mi = 0; _mi < 4; ++_mi) \
    _Pragma("unroll") \
    for (int _ni = 0; _ni < 2; ++_ni) \
      _Pragma("unroll") \
      for (int _kk = 0; _kk < 2; ++_kk) \
        acc[(g) * 4 + _mi][(nB) + _ni] = __builtin_amdgcn_mfma_f32_16x16x32_bf16( \
            a[_mi * 2 + _kk], bset[_ni * 2 + _kk], acc[(g) * 4 + _mi][(nB) + _ni], 0, 0, 0); \
} while (0)

#define PH_MID() do { \
  __builtin_amdgcn_s_barrier(); \
  asm volatile("s_waitcnt lgkmcnt(0)" ::: "memory"); \
  __builtin_amdgcn_sched_barrier(0); \
  __builtin_amdgcn_s_setprio(1); \
} while (0)

#define PH_END() do { \
  __builtin_amdgcn_s_setprio(0); \
  __builtin_amdgcn_s_barrier(); \
} while (0)

#define PH_END_VM(n) do { \
  __builtin_amdgcn_s_setprio(0); \
  asm volatile("s_waitcnt vmcnt(" #n ")" ::: "memory"); \
  __builtin_amdgcn_s_barrier(); \
} while (0)

__global__ __launch_bounds__(512, 2) void qkv_gemm_kernel(
    const u16* __restrict__ xb, const u16* __restrict__ wT,
    const float* __restrict__ bq, const float* __restrict__ bk, const float* __restrict__ bv,
    u16* __restrict__ qb, u16* __restrict__ kb, u16* __restrict__ vb)
{
  __shared__ u16 lds[65536];   // 128 KiB

  const int tid  = threadIdx.x;
  const int lane = tid & 63;
  const int wid  = tid >> 6;

  // XCD-chunked bijective swizzle: 1536 = 8 XCDs x 192
  const int orig = blockIdx.x;
  const int wg   = (orig & 7) * 192 + (orig >> 3);
  const int bm   = wg / 12;
  const int bn   = wg % 12;
  const int mat  = bn >> 2;
  const int col0 = (bn & 3) << 8;
  const int row0 = bm << 8;
  const u16* Wm = wT + ((size_t)mat << 20);
  const float* bias = (mat == 0) ? bq : (mat == 1) ? bk : bv;
  u16* outp = (mat == 0) ? qb : (mat == 1) ? kb : vb;

  const int wr = wid >> 2;             // 0..1
  const int wc = wid & 3;              // 0..3
  const int l15 = lane & 15, lhi = lane >> 4;

  // staging source (pre-swizzled so LDS dest stays linear)
  const int sr = lane >> 3;            // row within 8-row block
  const int sl = (lane & 7) ^ sr;      // logical 16B slot
  const u16* srcA = xb + (size_t)(row0 + sr) * DIM + sl * 8;
  const u16* srcB = Wm + (size_t)(col0 + sr) * DIM + sl * 8;

  // fragment phys-slot offsets (elems): phys = logical ^ (row&7)
  const int sx0 = (lhi ^ (l15 & 7)) << 3;
  const int sx1 = ((4 + lhi) ^ (l15 & 7)) << 3;
  const int abase = (wr * 128 + l15) * 64;
  const int bbase = (wc * 64 + l15) * 64;

  f32x4 acc[8][4] = {};
  short8 a[8], b01[4], b23[4];

  // prologue: kt0 fully + kt1 A halves; vmcnt(4) forces kt0, leaves kt1.A
  STAGE(0, 0, 0); STAGE(0, 1, 0); STAGE(1, 0, 0); STAGE(1, 1, 0);
  STAGE(0, 0, 1); STAGE(0, 1, 1);
  asm volatile("s_waitcnt vmcnt(4)" ::: "memory");
  __builtin_amdgcn_s_barrier();

  #pragma unroll 1
  for (int t = 0; t < 8; ++t) {
    const int kt = 2 * t;
    const bool pf = (t < 7);
    // ---- K-tile kt (dbuf0) ----
    // p1
    LDA(0, 0); LDB(0, b01, 0);
    STAGE(1, 0, kt + 1);
    asm volatile("s_waitcnt lgkmcnt(8)" ::: "memory");
    PH_MID(); MF(0, 0, b01); PH_END();
    // p2
    LDB(0, b23, 2);
    STAGE(1, 1, kt + 1);
    PH_MID(); MF(0, 2, b23); PH_END();
    // p3
    LDA(0, 1);
    PH_MID(); MF(1, 2, b23); PH_END();
    // p4 (b01 still live in regs)
    if (pf) STAGE(0, 0, kt + 2);
    PH_MID(); MF(1, 0, b01);
    if (pf) { PH_END_VM(2); } else { PH_END_VM(0); }
    // ---- K-tile kt+1 (dbuf1) ----
    // p5
    LDA(1, 0); LDB(1, b01, 0);
    if (pf) STAGE(0, 1, kt + 2);
    asm volatile("s_waitcnt lgkmcnt(8)" ::: "memory");
    PH_MID(); MF(0, 0, b01); PH_END();
    // p6
    LDB(1, b23, 2);
    if (pf) STAGE(1, 0, kt + 2);
    PH_MID(); MF(0, 2, b23); PH_END();
    // p7
    LDA(1, 1);
    if (pf) STAGE(1, 1, kt + 2);
    PH_MID(); MF(1, 2, b23); PH_END();
    // p8
    if (pf) { STAGE(0, 0, kt + 3); STAGE(0, 1, kt + 3); }
    PH_MID(); MF(1, 0, b01);
    if (pf) { PH_END_VM(4); } else { PH_END_VM(0); }
  }

  // ---- epilogue: bias + LDS-bounce transpose -> coalesced 16B stores ------
  {
    u16* ep = lds + wid * 8192;
    #pragma unroll
    for (int ni = 0; ni < 4; ++ni) {
      int gcol = col0 + wc * 64 + ni * 16 + l15;
      float bb = bias[gcol];
      #pragma unroll
      for (int mi = 0; mi < 8; ++mi)
        #pragma unroll
        for (int r = 0; r < 4; ++r) {
          int lr = mi * 16 + (lhi << 2) + r;
          int lc = ni * 16 + l15;
          ep[lr * 64 + (((lc >> 3) ^ (lr & 7)) << 3) + (lc & 7)] = f2b(acc[mi][ni][r] + bb);
        }
    }
    const int rr = lane >> 3;          // 0..7
    const int cc = lane & 7;           // 0..7
    u16* obase = outp + (size_t)(row0 + wr * 128) * DIM + col0 + wc * 64 + cc * 8;
    #pragma unroll
    for (int it = 0; it < 16; ++it) {
      int lr = it * 8 + rr;
      short8 v = *(const short8*)(ep + lr * 64 + ((cc ^ (lr & 7)) << 3));
      *(short8*)(obase + (size_t)lr * DIM) = v;
    }
  }
}

// ---------------- block-diagonal attention: one WG per (b, blk, h) -----------
// Independent blocks, multiple blocks/CU -> setprio around MFMA clusters is
// the documented positive case (m191: +4-7% attn).
__global__ __launch_bounds__(256) void blk_attn_kernel(
    const u16* __restrict__ qb, const u16* __restrict__ kb, const u16* __restrict__ vb,
    float* __restrict__ out)
{
  __shared__ u16 qs[64 * 72];
  __shared__ u16 ks[64 * 72];
  __shared__ u16 vts[64 * 72];
  __shared__ u16 ps[64 * 72];

  const int tid  = threadIdx.x;
  const int lane = tid & 63;
  const int wid  = tid >> 6;
  const int idx  = blockIdx.x;
  const int h    = idx & 15;
  const int blk  = (idx >> 4) & 127;
  const int b    = idx >> 11;
  const size_t s0 = (size_t)b * 8192 + (size_t)blk * 64;
  const int h0 = h * HDIM;

  {
    int i  = tid >> 2;
    int cg = (tid & 3) * 16;
    const u16* qg = qb + (s0 + i) * DIM + h0 + cg;
    *(short8*)(qs + i * 72 + cg)     = *(const short8*)qg;
    *(short8*)(qs + i * 72 + cg + 8) = *(const short8*)(qg + 8);
    const u16* kg = kb + (s0 + i) * DIM + h0 + cg;
    *(short8*)(ks + i * 72 + cg)     = *(const short8*)kg;
    *(short8*)(ks + i * 72 + cg + 8) = *(const short8*)(kg + 8);
    const u16* vg = vb + (s0 + i) * DIM + h0 + cg;
    short8 v0 = *(const short8*)vg;
    short8 v1 = *(const short8*)(vg + 8);
    #pragma unroll
    for (int e = 0; e < 8; ++e) {
      vts[(cg + e) * 72 + i]     = (u16)v0[e];
      vts[(cg + 8 + e) * 72 + i] = (u16)v1[e];
    }
  }
  __syncthreads();

  f32x4 S[4] = {};
  {
    short8 aq[2];
    #pragma unroll
    for (int kk = 0; kk < 2; ++kk)
      aq[kk] = *(const short8*)(qs + (wid * 16 + (lane & 15)) * 72 + kk * 32 + ((lane >> 4) << 3));
    __builtin_amdgcn_s_setprio(1);
    #pragma unroll
    for (int jt = 0; jt < 4; ++jt)
      #pragma unroll
      for (int kk = 0; kk < 2; ++kk) {
        short8 bk_ = *(const short8*)(ks + (jt * 16 + (lane & 15)) * 72 + kk * 32 + ((lane >> 4) << 3));
        S[jt] = __builtin_amdgcn_mfma_f32_16x16x32_bf16(aq[kk], bk_, S[jt], 0, 0, 0);
      }
    __builtin_amdgcn_s_setprio(0);
  }

  const float scale = 0.125f;
  float rinv[4];
  #pragma unroll
  for (int r = 0; r < 4; ++r) {
    float m = S[0][r] * scale;
    #pragma unroll
    for (int jt = 1; jt < 4; ++jt) m = fmaxf(m, S[jt][r] * scale);
    #pragma unroll
    for (int off = 1; off < 16; off <<= 1) m = fmaxf(m, __shfl_xor(m, off, 64));
    float s = 0.f;
    #pragma unroll
    for (int jt = 0; jt < 4; ++jt) {
      float e = __expf(S[jt][r] * scale - m);
      S[jt][r] = e;
      s += e;
    }
    #pragma unroll
    for (int off = 1; off < 16; off <<= 1) s += __shfl_xor(s, off, 64);
    rinv[r] = 1.0f / s;
  }

  #pragma unroll
  for (int jt = 0; jt < 4; ++jt)
    #pragma unroll
    for (int r = 0; r < 4; ++r)
      ps[(wid * 16 + ((lane >> 4) << 2) + r) * 72 + jt * 16 + (lane & 15)] = f2b(S[jt][r]);
  __syncthreads();

  f32x4 O[4] = {};
  {
    short8 pa[2];
    #pragma unroll
    for (int kk = 0; kk < 2; ++kk)
      pa[kk] = *(const short8*)(ps + (wid * 16 + (lane & 15)) * 72 + kk * 32 + ((lane >> 4) << 3));
    __builtin_amdgcn_s_setprio(1);
    #pragma unroll
    for (int dt = 0; dt < 4; ++dt)
      #pragma unroll
      for (int kk = 0; kk < 2; ++kk) {
        short8 bv_ = *(const short8*)(vts + (dt * 16 + (lane & 15)) * 72 + kk * 32 + ((lane >> 4) << 3));
        O[dt] = __builtin_amdgcn_mfma_f32_16x16x32_bf16(pa[kk], bv_, O[dt], 0, 0, 0);
      }
    __builtin_amdgcn_s_setprio(0);
  }

  #pragma unroll
  for (int dt = 0; dt < 4; ++dt)
    #pragma unroll
    for (int r = 0; r < 4; ++r)
      out[(s0 + wid * 16 + ((lane >> 4) << 2) + r) * DIM + h0 + dt * 16 + (lane & 15)] = O[dt][r] * rinv[r];
}

extern "C" void kernel_launch(void* const* d_in, const int* in_sizes, int n_in,
                              void* d_out, int out_size, void* d_ws, size_t ws_size,
                              hipStream_t stream) {
  const float* x  = (const float*)d_in[0];
  const float* Wq = (const float*)d_in[1];
  const float* bq = (const float*)d_in[2];
  const float* Wk = (const float*)d_in[3];
  const float* bk = (const float*)d_in[4];
  const float* Wv = (const float*)d_in[5];
  const float* bv = (const float*)d_in[6];
  float* out = (float*)d_out;

  char* ws = (char*)d_ws;
  u16* xb = (u16*)ws;                          // 67,108,864 B
  u16* wT = (u16*)(ws + 67108864);             // 6,291,456 B
  u16* qb = (u16*)(ws + 73400320);             // 67,108,864 B
  u16* kb = (u16*)(ws + 140509184);            // 67,108,864 B
  u16* vb = (u16*)(ws + 207618048);            // 67,108,864 B

  cvt_fused_kernel<<<17920, 256, 0, stream>>>(x, Wq, Wk, Wv, xb, wT);
  qkv_gemm_kernel<<<1536, 512, 0, stream>>>(xb, wT, bq, bk, bv, qb, kb, vb);
  blk_attn_kernel<<<8192, 256, 0, stream>>>(qb, kb, vb, out);
}